// Round 1
// baseline (469.855 us; speedup 1.0000x reference)
//
#include <hip/hip_runtime.h>

// NaiveCustomLSTM: V is block-diagonal (20 blocks of 32), U is (nearly) diagonal.
// => 2560 independent 32-wide LSTMs (128 batch x 20 blocks), 512 steps each.
// One wave per unit. Lanes 0-31: gates i,f for n=lane; lanes 32-63: gates g,o.
// h[k] broadcast via v_readlane (k is wave-uniform); V columns + x in registers.

#define TT 512
#define HN 640
#define BN 128

__device__ __forceinline__ float rl(float v, int s) {
  return __int_as_float(__builtin_amdgcn_readlane(__float_as_int(v), s));
}

__global__ __launch_bounds__(256) void lstm_kernel(
    const float* __restrict__ x,
    const float* __restrict__ Ui, const float* __restrict__ Vi, const float* __restrict__ bi,
    const float* __restrict__ Uf, const float* __restrict__ Vf, const float* __restrict__ bf,
    const float* __restrict__ Uc, const float* __restrict__ Vc, const float* __restrict__ bc,
    const float* __restrict__ Uo, const float* __restrict__ Vo, const float* __restrict__ bo,
    float* __restrict__ out) {
  const int unit = (blockIdx.x * 256 + threadIdx.x) >> 6;  // 0..2559
  const int lane = threadIdx.x & 63;
  const int j = unit >> 7;   // hidden block 0..19
  const int b = unit & 127;  // batch
  const int gp = lane >> 5;  // 0: gates i,f ; 1: gates g(c-cand),o
  const int n = lane & 31;
  const int col = j * 32 + n;

  const float* UG1 = gp ? Uc : Ui;
  const float* UG2 = gp ? Uo : Uf;
  const float* VG1 = gp ? Vc : Vi;
  const float* VG2 = gp ? Vo : Vf;
  const float* bG1 = gp ? bc : bi;
  const float* bG2 = gp ? bo : bf;

  // Effective input weights for this block (from U mask structure).
  float w11 = 0.f, w21 = 0.f, w12 = 0.f, w22 = 0.f;
  int f1 = 0, f2 = 0;
  if (j < 16) {
    f1 = f2 = j;
    w11 = UG1[j * HN + col];
    w12 = UG2[j * HN + col];
    if (j == 0) {
      w11 += UG1[16 * HN + col]; w12 += UG2[16 * HN + col];
      w21  = UG1[17 * HN + col]; w22  = UG2[17 * HN + col];
      f2 = 1;
    } else if (j == 2) {
      w11 += UG1[18 * HN + col]; w12 += UG2[18 * HN + col];
      w21  = UG1[19 * HN + col]; w22  = UG2[19 * HN + col];
      f2 = 3;
    }
  }
  const float bb1 = bG1[col];
  const float bb2 = bG2[col];

  // Recurrent weight columns: V_G[(j*32+k), col], k=0..31 (2 gates per lane).
  float v1r[32], v2r[32];
#pragma unroll
  for (int k = 0; k < 32; ++k) {
    v1r[k] = VG1[(j * 32 + k) * HN + col];
    v2r[k] = VG2[(j * 32 + k) * HN + col];
  }

  // Stage this unit's input sequence in registers: lane holds t = i*64+lane.
  float xa[8], xb[8];
#pragma unroll
  for (int i = 0; i < 8; ++i) {
    const int t = i * 64 + lane;
    xa[i] = x[(b * TT + t) * 16 + f1];
    xb[i] = x[(b * TT + t) * 16 + f2];
  }

  // Uniform nonlinearity: val = A * rcp(1 + exp2(B*a)) + C
  // gate1: lo = sigmoid(i) (A=1,B=-log2e,C=0); hi = tanh(g) (A=2,B=-2log2e,C=-1)
  // gate2: sigmoid for both halves (f and o).
  const float LOG2E = 1.44269504088896340736f;
  const float Bc1 = gp ? (-2.f * LOG2E) : -LOG2E;
  const float Ac1 = gp ? 2.f : 1.f;
  const float Cc1 = gp ? -1.f : 0.f;

  float h = 0.f, c = 0.f;  // valid state lives on lanes 0-31; upper half mirrors junk
  int ob = b * TT * HN + col;
#pragma unroll
  for (int i = 0; i < 8; ++i) {
    const float xc1 = xa[i];
    const float xc2 = xb[i];
    for (int s = 0; s < 64; ++s) {
      const float x1 = rl(xc1, s);
      const float x2 = rl(xc2, s);
      float a1 = fmaf(x2, w21, fmaf(x1, w11, bb1));
      float a2 = fmaf(x2, w22, fmaf(x1, w12, bb2));
      float a1b = 0.f, a2b = 0.f;
#pragma unroll
      for (int k = 0; k < 32; k += 2) {
        const float hk0 = rl(h, k);
        const float hk1 = rl(h, k + 1);
        a1  = fmaf(hk0, v1r[k],     a1);
        a2  = fmaf(hk0, v2r[k],     a2);
        a1b = fmaf(hk1, v1r[k + 1], a1b);
        a2b = fmaf(hk1, v2r[k + 1], a2b);
      }
      a1 += a1b;
      a2 += a2b;
      // lo: g1=sig(i), g2=sig(f); hi: g1=tanh(g), g2=sig(o)
      const float g1 = fmaf(Ac1, __builtin_amdgcn_rcpf(1.f + __builtin_amdgcn_exp2f(Bc1 * a1)), Cc1);
      const float g2 = __builtin_amdgcn_rcpf(1.f + __builtin_amdgcn_exp2f(-LOG2E * a2));
      const float p1 = __shfl_xor(g1, 32);  // lo gets tanh(g); hi gets sig(i)
      const float p2 = __shfl_xor(g2, 32);  // lo gets sig(o);  hi gets sig(f)
      c = fmaf(g2, c, g1 * p1);             // lo: c = sig(f)*c + sig(i)*tanh(g)
      const float tc = fmaf(2.f, __builtin_amdgcn_rcpf(1.f + __builtin_amdgcn_exp2f(-2.f * LOG2E * c)), -1.f);
      h = p2 * tc;                          // lo: h = sig(o)*tanh(c)
      if (lane < 32) out[ob] = h;
      ob += HN;
    }
  }
  if (lane < 32) {
    out[BN * TT * HN + b * HN + col] = h;                 // h_t
    out[BN * TT * HN + BN * HN + b * HN + col] = c;       // c_t
  }
}

extern "C" void kernel_launch(void* const* d_in, const int* in_sizes, int n_in,
                              void* d_out, int out_size, void* d_ws, size_t ws_size,
                              hipStream_t stream) {
  (void)in_sizes; (void)n_in; (void)d_ws; (void)ws_size; (void)out_size;
  const float* x  = (const float*)d_in[0];
  const float* Ui = (const float*)d_in[1];
  const float* Vi = (const float*)d_in[2];
  const float* bi = (const float*)d_in[3];
  const float* Uf = (const float*)d_in[4];
  const float* Vf = (const float*)d_in[5];
  const float* bf = (const float*)d_in[6];
  const float* Uc = (const float*)d_in[7];
  const float* Vc = (const float*)d_in[8];
  const float* bc = (const float*)d_in[9];
  const float* Uo = (const float*)d_in[10];
  const float* Vo = (const float*)d_in[11];
  const float* bo = (const float*)d_in[12];
  float* out = (float*)d_out;

  dim3 grid(640);   // 2560 units / 4 waves per workgroup
  dim3 block(256);
  hipLaunchKernelGGL(lstm_kernel, grid, block, 0, stream,
                     x, Ui, Vi, bi, Uf, Vf, bf, Uc, Vc, bc, Uo, Vo, bo, out);
}

// Round 5
// 397.804 us; speedup vs baseline: 1.1811x; 1.1811x over previous
//
#include <hip/hip_runtime.h>

// NaiveCustomLSTM: V block-diagonal (20 blocks of 32), U (nearly) diagonal.
// => 2560 independent 32-wide LSTMs (128 batch x 20 blocks), 512 steps.
// One wave per unit, one wave per workgroup (grid=2560 -> exactly 10 waves/CU).
// Lanes 0-31: gates i,f for n=lane; lanes 32-63: gates g,o for n=lane-32.
//
// R3/R4 bug (fixed here): pre1/pre2 folded PER-LANE weights (w11,bb1 depend on
// n=lane&31, B1 depends on gp) and were then broadcast wave-wide via readlane,
// handing every lane the value computed with lane s's weights. Only raw x
// (lane-uniform in n; varies only in t) may be broadcast; per-lane weights are
// applied after the broadcast, as in the passing R1 kernel.
//
// h broadcast via LDS: ds_write_b32 + 8x broadcast ds_read_b128 (same-address,
// conflict-free); same-wave DS ops execute in order. Dot product as
// v_pk_fma_f32 pairing k/k+1; sigmoid/tanh exp2 scales pre-folded per-lane
// into weights so the accumulator IS the exp2 argument.

#define TT 512
#define HN 640
#define BN 128

typedef float f2 __attribute__((ext_vector_type(2)));
typedef float f4v __attribute__((ext_vector_type(4)));

__device__ __forceinline__ float rl(float v, int s) {
  return __int_as_float(__builtin_amdgcn_readlane(__float_as_int(v), s));
}

// acc.{x,y} += w.{x,y} * h.{x,y}  (all VGPR pairs; plain packed fp32 FMA)
__device__ __forceinline__ void pkfma(f2& acc, f2 w, f2 h) {
  asm("v_pk_fma_f32 %0, %1, %2, %0" : "+v"(acc) : "v"(w), "v"(h));
}

__global__ __launch_bounds__(64) void lstm_kernel(
    const float* __restrict__ x,
    const float* __restrict__ Ui, const float* __restrict__ Vi, const float* __restrict__ bi,
    const float* __restrict__ Uf, const float* __restrict__ Vf, const float* __restrict__ bf,
    const float* __restrict__ Uc, const float* __restrict__ Vc, const float* __restrict__ bc,
    const float* __restrict__ Uo, const float* __restrict__ Vo, const float* __restrict__ bo,
    float* __restrict__ out) {
  __shared__ __align__(16) float hsh[64];  // [0..31] valid h, [32..63] junk sink

  const int unit = blockIdx.x;   // 0..2559
  const int lane = threadIdx.x;  // 0..63
  const int j = unit >> 7;       // hidden block 0..19
  const int b = unit & 127;      // batch
  const int gp = lane >> 5;      // 0: gates i,f ; 1: gates g,o
  const int n = lane & 31;
  const int col = j * 32 + n;

  const float* UG1 = gp ? Uc : Ui;
  const float* UG2 = gp ? Uo : Uf;
  const float* VG1 = gp ? Vc : Vi;
  const float* VG2 = gp ? Vo : Vf;
  const float* bG1 = gp ? bc : bi;
  const float* bG2 = gp ? bo : bf;

  const float LOG2E = 1.44269504088896340736f;
  // gate1: lo = sigmoid(i) (scale -log2e); hi = tanh(g) (scale -2log2e)
  // gate2: sigmoid (f / o) for both halves.
  const float B1 = gp ? (-2.f * LOG2E) : -LOG2E;
  const float B2 = -LOG2E;
  const float Ac1 = gp ? 2.f : 1.f;
  const float Cc1 = gp ? -1.f : 0.f;

  // Effective input weights for this block (from U mask structure).
  float w11 = 0.f, w21 = 0.f, w12 = 0.f, w22 = 0.f;
  int f1 = 0, f2i = 0;
  if (j < 16) {
    f1 = f2i = j;
    w11 = UG1[j * HN + col];
    w12 = UG2[j * HN + col];
    if (j == 0) {
      w11 += UG1[16 * HN + col]; w12 += UG2[16 * HN + col];
      w21  = UG1[17 * HN + col]; w22  = UG2[17 * HN + col];
      f2i = 1;
    } else if (j == 2) {
      w11 += UG1[18 * HN + col]; w12 += UG2[18 * HN + col];
      w21  = UG1[19 * HN + col]; w22  = UG2[19 * HN + col];
      f2i = 3;
    }
  }
  // Pre-scale per-lane input weights/bias by the exp2 factor (stays per-lane!).
  const float ws11 = B1 * w11, ws21 = B1 * w21, bs1 = B1 * bG1[col];
  const float ws12 = B2 * w12, ws22 = B2 * w22, bs2 = B2 * bG2[col];

  // Recurrent weight columns, pre-scaled, paired over k:
  // wA[kp] = {B1*V1[2kp,col], B1*V1[2kp+1,col]}, wB likewise with B2*V2.
  f2 wA[16], wB[16];
#pragma unroll
  for (int kp = 0; kp < 16; ++kp) {
    wA[kp].x = B1 * VG1[(j * 32 + 2 * kp) * HN + col];
    wA[kp].y = B1 * VG1[(j * 32 + 2 * kp + 1) * HN + col];
    wB[kp].x = B2 * VG2[(j * 32 + 2 * kp) * HN + col];
    wB[kp].y = B2 * VG2[(j * 32 + 2 * kp + 1) * HN + col];
  }

  // Stage RAW input sequence in registers (lane-uniform in n: only t varies).
  // Lane holds t = i*64+lane.
  float xa[8], xb[8];
#pragma unroll
  for (int i = 0; i < 8; ++i) {
    const int t = i * 64 + lane;
    xa[i] = x[(b * TT + t) * 16 + f1];
    xb[i] = x[(b * TT + t) * 16 + f2i];
  }

  float h = 0.f, c = 0.f;  // valid in lanes 0-31; upper half carries junk
  int ob = b * TT * HN + col;
#pragma unroll
  for (int i = 0; i < 8; ++i) {
    const float xc1 = xa[i];
    const float xc2 = xb[i];
    for (int s = 0; s < 64; ++s) {
      const float x1 = rl(xc1, s);  // raw x — safe to broadcast
      const float x2 = rl(xc2, s);
      // Per-lane scaled x-contribution (weights applied AFTER broadcast).
      const float sx1 = fmaf(x2, ws21, fmaf(x1, ws11, bs1));
      const float sx2 = fmaf(x2, ws22, fmaf(x1, ws12, bs2));
      // Broadcast h through LDS. All lanes store (no divergence); only
      // [0..31] is meaningful. Same-wave DS ops execute in order.
      hsh[lane] = h;
      __builtin_amdgcn_wave_barrier();
      f2 hp[16];
#pragma unroll
      for (int m = 0; m < 8; ++m) {
        f4v q;
        __builtin_memcpy(&q, &hsh[4 * m], 16);  // broadcast ds_read_b128
        hp[2 * m]     = __builtin_shufflevector(q, q, 0, 1);
        hp[2 * m + 1] = __builtin_shufflevector(q, q, 2, 3);
      }
      __builtin_amdgcn_wave_barrier();
      f2 aA = {sx1, 0.f}, aB = {sx2, 0.f};
#pragma unroll
      for (int kp = 0; kp < 16; ++kp) {
        pkfma(aA, wA[kp], hp[kp]);
        pkfma(aB, wB[kp], hp[kp]);
      }
      const float a1 = aA.x + aA.y;  // = B1 * gate1 preactivation
      const float a2 = aB.x + aB.y;  // = B2 * gate2 preactivation
      const float e1 = __builtin_amdgcn_exp2f(a1);
      const float e2 = __builtin_amdgcn_exp2f(a2);
      // lo: g1=sig(i), g2=sig(f); hi: g1=tanh(g), g2=sig(o)
      const float g1 = fmaf(Ac1, __builtin_amdgcn_rcpf(1.f + e1), Cc1);
      const float g2 = __builtin_amdgcn_rcpf(1.f + e2);
      const float p1 = __shfl_xor(g1, 32);  // lo gets tanh(g); hi gets sig(i)
      const float p2 = __shfl_xor(g2, 32);  // lo gets sig(o);  hi gets sig(f)
      c = fmaf(g2, c, g1 * p1);             // lo: c = sig(f)*c + sig(i)*tanh(g)
      const float tc = fmaf(
          2.f,
          __builtin_amdgcn_rcpf(1.f + __builtin_amdgcn_exp2f(-2.f * LOG2E * c)),
          -1.f);
      h = p2 * tc;                          // lo: h = sig(o)*tanh(c)
      if (lane < 32) out[ob] = h;
      ob += HN;
    }
  }
  if (lane < 32) {
    out[BN * TT * HN + b * HN + col] = h;             // h_t
    out[BN * TT * HN + BN * HN + b * HN + col] = c;   // c_t
  }
}

extern "C" void kernel_launch(void* const* d_in, const int* in_sizes, int n_in,
                              void* d_out, int out_size, void* d_ws, size_t ws_size,
                              hipStream_t stream) {
  (void)in_sizes; (void)n_in; (void)d_ws; (void)ws_size; (void)out_size;
  const float* x  = (const float*)d_in[0];
  const float* Ui = (const float*)d_in[1];
  const float* Vi = (const float*)d_in[2];
  const float* bi = (const float*)d_in[3];
  const float* Uf = (const float*)d_in[4];
  const float* Vf = (const float*)d_in[5];
  const float* bf = (const float*)d_in[6];
  const float* Uc = (const float*)d_in[7];
  const float* Vc = (const float*)d_in[8];
  const float* bc = (const float*)d_in[9];
  const float* Uo = (const float*)d_in[10];
  const float* Vo = (const float*)d_in[11];
  const float* bo = (const float*)d_in[12];
  float* out = (float*)d_out;

  dim3 grid(2560);  // one wave per workgroup -> exactly 10 waves/CU, balanced
  dim3 block(64);
  hipLaunchKernelGGL(lstm_kernel, grid, block, 0, stream,
                     x, Ui, Vi, bi, Uf, Vf, bf, Uc, Vc, bc, Uo, Vo, bo, out);
}

// Round 6
// 393.376 us; speedup vs baseline: 1.1944x; 1.0113x over previous
//
#include <hip/hip_runtime.h>

// NaiveCustomLSTM: V block-diagonal (20 blocks of 32), U (nearly) diagonal.
// => 2560 independent 32-wide LSTMs (128 batch x 20 blocks), 512 steps.
// One wave per unit, one wave per workgroup (grid=2560 -> 10 waves/CU).
// Lanes 0-31: gates i,f for n=lane; lanes 32-63: gates g,o for n=lane-32.
//
// R6 codegen cleanup vs R5 (math identical to the passing R5):
//  - hp loaded with ONE __builtin_memcpy(hp, hsh, 128) -> 8x ds_read_b128
//    straight into the FMA operand registers (R5's per-q shufflevector
//    extraction cost ~32 v_mov/step).
//  - v_pk_fma_f32 via __builtin_elementwise_fma on float2 (inline asm "v"
//    constraints forced operand copies; intrinsic lets regalloc fold).
//
// h broadcast via LDS: ds_write_b32 + broadcast ds_read_b128 (same-address,
// conflict-free); same-wave DS ops execute in order. Sigmoid/tanh exp2
// scales pre-folded per-lane into weights so the accumulator IS the exp2 arg.
// Only raw x (lane-uniform in n) is broadcast via readlane; per-lane weights
// applied after broadcast (R3/R4 bug: broadcasting per-lane-weighted values).

#define TT 512
#define HN 640
#define BN 128

typedef float f2 __attribute__((ext_vector_type(2)));

__device__ __forceinline__ float rl(float v, int s) {
  return __int_as_float(__builtin_amdgcn_readlane(__float_as_int(v), s));
}

__global__ __launch_bounds__(64) void lstm_kernel(
    const float* __restrict__ x,
    const float* __restrict__ Ui, const float* __restrict__ Vi, const float* __restrict__ bi,
    const float* __restrict__ Uf, const float* __restrict__ Vf, const float* __restrict__ bf,
    const float* __restrict__ Uc, const float* __restrict__ Vc, const float* __restrict__ bc,
    const float* __restrict__ Uo, const float* __restrict__ Vo, const float* __restrict__ bo,
    float* __restrict__ out) {
  __shared__ __align__(16) float hsh[64];  // [0..31] valid h, [32..63] junk sink

  const int unit = blockIdx.x;   // 0..2559
  const int lane = threadIdx.x;  // 0..63
  const int j = unit >> 7;       // hidden block 0..19
  const int b = unit & 127;      // batch
  const int gp = lane >> 5;      // 0: gates i,f ; 1: gates g,o
  const int n = lane & 31;
  const int col = j * 32 + n;

  const float* UG1 = gp ? Uc : Ui;
  const float* UG2 = gp ? Uo : Uf;
  const float* VG1 = gp ? Vc : Vi;
  const float* VG2 = gp ? Vo : Vf;
  const float* bG1 = gp ? bc : bi;
  const float* bG2 = gp ? bo : bf;

  const float LOG2E = 1.44269504088896340736f;
  // gate1: lo = sigmoid(i) (scale -log2e); hi = tanh(g) (scale -2log2e)
  // gate2: sigmoid (f / o) for both halves.
  const float B1 = gp ? (-2.f * LOG2E) : -LOG2E;
  const float B2 = -LOG2E;
  const float Ac1 = gp ? 2.f : 1.f;
  const float Cc1 = gp ? -1.f : 0.f;

  // Effective input weights for this block (from U mask structure).
  float w11 = 0.f, w21 = 0.f, w12 = 0.f, w22 = 0.f;
  int f1 = 0, f2i = 0;
  if (j < 16) {
    f1 = f2i = j;
    w11 = UG1[j * HN + col];
    w12 = UG2[j * HN + col];
    if (j == 0) {
      w11 += UG1[16 * HN + col]; w12 += UG2[16 * HN + col];
      w21  = UG1[17 * HN + col]; w22  = UG2[17 * HN + col];
      f2i = 1;
    } else if (j == 2) {
      w11 += UG1[18 * HN + col]; w12 += UG2[18 * HN + col];
      w21  = UG1[19 * HN + col]; w22  = UG2[19 * HN + col];
      f2i = 3;
    }
  }
  // Pre-scale per-lane input weights/bias by the exp2 factor (stays per-lane).
  const float ws11 = B1 * w11, ws21 = B1 * w21, bs1 = B1 * bG1[col];
  const float ws12 = B2 * w12, ws22 = B2 * w22, bs2 = B2 * bG2[col];

  // Recurrent weight columns, pre-scaled, paired over k:
  // wA[kp] = {B1*V1[2kp,col], B1*V1[2kp+1,col]}, wB likewise with B2*V2.
  f2 wA[16], wB[16];
#pragma unroll
  for (int kp = 0; kp < 16; ++kp) {
    wA[kp].x = B1 * VG1[(j * 32 + 2 * kp) * HN + col];
    wA[kp].y = B1 * VG1[(j * 32 + 2 * kp + 1) * HN + col];
    wB[kp].x = B2 * VG2[(j * 32 + 2 * kp) * HN + col];
    wB[kp].y = B2 * VG2[(j * 32 + 2 * kp + 1) * HN + col];
  }

  // Stage RAW input sequence in registers (lane-uniform in n: only t varies).
  // Lane holds t = i*64+lane.
  float xa[8], xb[8];
#pragma unroll
  for (int i = 0; i < 8; ++i) {
    const int t = i * 64 + lane;
    xa[i] = x[(b * TT + t) * 16 + f1];
    xb[i] = x[(b * TT + t) * 16 + f2i];
  }

  float h = 0.f, c = 0.f;  // valid in lanes 0-31; upper half carries junk
  int ob = b * TT * HN + col;
#pragma unroll
  for (int i = 0; i < 8; ++i) {
    const float xc1 = xa[i];
    const float xc2 = xb[i];
    for (int s = 0; s < 64; ++s) {
      const float x1 = rl(xc1, s);  // raw x — safe to broadcast
      const float x2 = rl(xc2, s);
      // Per-lane scaled x-contribution (weights applied AFTER broadcast).
      const float sx1 = fmaf(x2, ws21, fmaf(x1, ws11, bs1));
      const float sx2 = fmaf(x2, ws22, fmaf(x1, ws12, bs2));
      // Broadcast h through LDS. All lanes store (no divergence); only
      // [0..31] is meaningful. Same-wave DS ops execute in order.
      hsh[lane] = h;
      __builtin_amdgcn_wave_barrier();
      f2 hp[16];
      __builtin_memcpy(hp, hsh, 128);  // 8x broadcast ds_read_b128, in place
      __builtin_amdgcn_wave_barrier();
      f2 aA = {sx1, 0.f}, aB = {sx2, 0.f};
#pragma unroll
      for (int kp = 0; kp < 16; ++kp) {
        aA = __builtin_elementwise_fma(wA[kp], hp[kp], aA);  // v_pk_fma_f32
        aB = __builtin_elementwise_fma(wB[kp], hp[kp], aB);
      }
      const float a1 = aA.x + aA.y;  // = B1 * gate1 preactivation
      const float a2 = aB.x + aB.y;  // = B2 * gate2 preactivation
      const float e1 = __builtin_amdgcn_exp2f(a1);
      const float e2 = __builtin_amdgcn_exp2f(a2);
      // lo: g1=sig(i), g2=sig(f); hi: g1=tanh(g), g2=sig(o)
      const float g1 = fmaf(Ac1, __builtin_amdgcn_rcpf(1.f + e1), Cc1);
      const float g2 = __builtin_amdgcn_rcpf(1.f + e2);
      const float p1 = __shfl_xor(g1, 32);  // lo gets tanh(g); hi gets sig(i)
      const float p2 = __shfl_xor(g2, 32);  // lo gets sig(o);  hi gets sig(f)
      c = fmaf(g2, c, g1 * p1);             // lo: c = sig(f)*c + sig(i)*tanh(g)
      const float tc = fmaf(
          2.f,
          __builtin_amdgcn_rcpf(1.f + __builtin_amdgcn_exp2f(-2.f * LOG2E * c)),
          -1.f);
      h = p2 * tc;                          // lo: h = sig(o)*tanh(c)
      if (lane < 32) out[ob] = h;
      ob += HN;
    }
  }
  if (lane < 32) {
    out[BN * TT * HN + b * HN + col] = h;             // h_t
    out[BN * TT * HN + BN * HN + b * HN + col] = c;   // c_t
  }
}

extern "C" void kernel_launch(void* const* d_in, const int* in_sizes, int n_in,
                              void* d_out, int out_size, void* d_ws, size_t ws_size,
                              hipStream_t stream) {
  (void)in_sizes; (void)n_in; (void)d_ws; (void)ws_size; (void)out_size;
  const float* x  = (const float*)d_in[0];
  const float* Ui = (const float*)d_in[1];
  const float* Vi = (const float*)d_in[2];
  const float* bi = (const float*)d_in[3];
  const float* Uf = (const float*)d_in[4];
  const float* Vf = (const float*)d_in[5];
  const float* bf = (const float*)d_in[6];
  const float* Uc = (const float*)d_in[7];
  const float* Vc = (const float*)d_in[8];
  const float* bc = (const float*)d_in[9];
  const float* Uo = (const float*)d_in[10];
  const float* Vo = (const float*)d_in[11];
  const float* bo = (const float*)d_in[12];
  float* out = (float*)d_out;

  dim3 grid(2560);  // one wave per workgroup -> exactly 10 waves/CU, balanced
  dim3 block(64);
  hipLaunchKernelGGL(lstm_kernel, grid, block, 0, stream,
                     x, Ui, Vi, bi, Uf, Vf, bf, Uc, Vc, bc, Uo, Vo, bo, out);
}

// Round 7
// 391.661 us; speedup vs baseline: 1.1996x; 1.0044x over previous
//
#include <hip/hip_runtime.h>

// NaiveCustomLSTM: V block-diagonal (20 blocks of 32), U (nearly) diagonal.
// => 2560 independent 32-wide LSTMs (128 batch x 20 blocks), 512 steps.
// One wave per unit, one wave per workgroup (grid=2560 -> 10 waves/CU).
// Lanes 0-31: gates i,f for n=lane; lanes 32-63: gates g,o for n=lane-32.
//
// R7 change (single variable vs R6): __launch_bounds__(64, 3).
// R1-R6 ran at VGPR_Count=72 -- too small for the ~125-reg working set
// (wA+wB = 64 regs of V-weights, hp = 32, xa/xb = 16). The compiler was
// re-materializing the V-weight loads INSIDE the 512-step loop (no scratch
// traffic, but ~64 L1/L2 VMEM reloads per step -> latency + issue overhead).
// min-3-waves/EU caps VGPRs at ~170: working set stays register-resident,
// and 2560 waves still fit 3/SIMD co-resident (need only 2.5).
//
// h broadcast via LDS: ds_write_b32 + broadcast ds_read_b128 (same-address,
// conflict-free); same-wave DS ops execute in order. Sigmoid/tanh exp2
// scales pre-folded per-lane into weights so the accumulator IS the exp2 arg.
// Only raw x (lane-uniform in n) is broadcast via readlane; per-lane weights
// applied after broadcast (R3/R4 bug: broadcasting per-lane-weighted values).

#define TT 512
#define HN 640
#define BN 128

typedef float f2 __attribute__((ext_vector_type(2)));

__device__ __forceinline__ float rl(float v, int s) {
  return __int_as_float(__builtin_amdgcn_readlane(__float_as_int(v), s));
}

__global__ __launch_bounds__(64, 3) void lstm_kernel(
    const float* __restrict__ x,
    const float* __restrict__ Ui, const float* __restrict__ Vi, const float* __restrict__ bi,
    const float* __restrict__ Uf, const float* __restrict__ Vf, const float* __restrict__ bf,
    const float* __restrict__ Uc, const float* __restrict__ Vc, const float* __restrict__ bc,
    const float* __restrict__ Uo, const float* __restrict__ Vo, const float* __restrict__ bo,
    float* __restrict__ out) {
  __shared__ __align__(16) float hsh[64];  // [0..31] valid h, [32..63] junk sink

  const int unit = blockIdx.x;   // 0..2559
  const int lane = threadIdx.x;  // 0..63
  const int j = unit >> 7;       // hidden block 0..19
  const int b = unit & 127;      // batch
  const int gp = lane >> 5;      // 0: gates i,f ; 1: gates g,o
  const int n = lane & 31;
  const int col = j * 32 + n;

  const float* UG1 = gp ? Uc : Ui;
  const float* UG2 = gp ? Uo : Uf;
  const float* VG1 = gp ? Vc : Vi;
  const float* VG2 = gp ? Vo : Vf;
  const float* bG1 = gp ? bc : bi;
  const float* bG2 = gp ? bo : bf;

  const float LOG2E = 1.44269504088896340736f;
  // gate1: lo = sigmoid(i) (scale -log2e); hi = tanh(g) (scale -2log2e)
  // gate2: sigmoid (f / o) for both halves.
  const float B1 = gp ? (-2.f * LOG2E) : -LOG2E;
  const float B2 = -LOG2E;
  const float Ac1 = gp ? 2.f : 1.f;
  const float Cc1 = gp ? -1.f : 0.f;

  // Effective input weights for this block (from U mask structure).
  float w11 = 0.f, w21 = 0.f, w12 = 0.f, w22 = 0.f;
  int f1 = 0, f2i = 0;
  if (j < 16) {
    f1 = f2i = j;
    w11 = UG1[j * HN + col];
    w12 = UG2[j * HN + col];
    if (j == 0) {
      w11 += UG1[16 * HN + col]; w12 += UG2[16 * HN + col];
      w21  = UG1[17 * HN + col]; w22  = UG2[17 * HN + col];
      f2i = 1;
    } else if (j == 2) {
      w11 += UG1[18 * HN + col]; w12 += UG2[18 * HN + col];
      w21  = UG1[19 * HN + col]; w22  = UG2[19 * HN + col];
      f2i = 3;
    }
  }
  // Pre-scale per-lane input weights/bias by the exp2 factor (stays per-lane).
  const float ws11 = B1 * w11, ws21 = B1 * w21, bs1 = B1 * bG1[col];
  const float ws12 = B2 * w12, ws22 = B2 * w22, bs2 = B2 * bG2[col];

  // Recurrent weight columns, pre-scaled, paired over k:
  // wA[kp] = {B1*V1[2kp,col], B1*V1[2kp+1,col]}, wB likewise with B2*V2.
  f2 wA[16], wB[16];
#pragma unroll
  for (int kp = 0; kp < 16; ++kp) {
    wA[kp].x = B1 * VG1[(j * 32 + 2 * kp) * HN + col];
    wA[kp].y = B1 * VG1[(j * 32 + 2 * kp + 1) * HN + col];
    wB[kp].x = B2 * VG2[(j * 32 + 2 * kp) * HN + col];
    wB[kp].y = B2 * VG2[(j * 32 + 2 * kp + 1) * HN + col];
  }

  // Stage RAW input sequence in registers (lane-uniform in n: only t varies).
  // Lane holds t = i*64+lane.
  float xa[8], xb[8];
#pragma unroll
  for (int i = 0; i < 8; ++i) {
    const int t = i * 64 + lane;
    xa[i] = x[(b * TT + t) * 16 + f1];
    xb[i] = x[(b * TT + t) * 16 + f2i];
  }

  float h = 0.f, c = 0.f;  // valid in lanes 0-31; upper half carries junk
  int ob = b * TT * HN + col;
#pragma unroll
  for (int i = 0; i < 8; ++i) {
    const float xc1 = xa[i];
    const float xc2 = xb[i];
    for (int s = 0; s < 64; ++s) {
      const float x1 = rl(xc1, s);  // raw x — safe to broadcast
      const float x2 = rl(xc2, s);
      // Per-lane scaled x-contribution (weights applied AFTER broadcast).
      const float sx1 = fmaf(x2, ws21, fmaf(x1, ws11, bs1));
      const float sx2 = fmaf(x2, ws22, fmaf(x1, ws12, bs2));
      // Broadcast h through LDS. All lanes store (no divergence); only
      // [0..31] is meaningful. Same-wave DS ops execute in order.
      hsh[lane] = h;
      __builtin_amdgcn_wave_barrier();
      f2 hp[16];
      __builtin_memcpy(hp, hsh, 128);  // 8x broadcast ds_read_b128, in place
      __builtin_amdgcn_wave_barrier();
      f2 aA = {sx1, 0.f}, aB = {sx2, 0.f};
#pragma unroll
      for (int kp = 0; kp < 16; ++kp) {
        aA = __builtin_elementwise_fma(wA[kp], hp[kp], aA);  // v_pk_fma_f32
        aB = __builtin_elementwise_fma(wB[kp], hp[kp], aB);
      }
      const float a1 = aA.x + aA.y;  // = B1 * gate1 preactivation
      const float a2 = aB.x + aB.y;  // = B2 * gate2 preactivation
      const float e1 = __builtin_amdgcn_exp2f(a1);
      const float e2 = __builtin_amdgcn_exp2f(a2);
      // lo: g1=sig(i), g2=sig(f); hi: g1=tanh(g), g2=sig(o)
      const float g1 = fmaf(Ac1, __builtin_amdgcn_rcpf(1.f + e1), Cc1);
      const float g2 = __builtin_amdgcn_rcpf(1.f + e2);
      const float p1 = __shfl_xor(g1, 32);  // lo gets tanh(g); hi gets sig(i)
      const float p2 = __shfl_xor(g2, 32);  // lo gets sig(o);  hi gets sig(f)
      c = fmaf(g2, c, g1 * p1);             // lo: c = sig(f)*c + sig(i)*tanh(g)
      const float tc = fmaf(
          2.f,
          __builtin_amdgcn_rcpf(1.f + __builtin_amdgcn_exp2f(-2.f * LOG2E * c)),
          -1.f);
      h = p2 * tc;                          // lo: h = sig(o)*tanh(c)
      if (lane < 32) out[ob] = h;
      ob += HN;
    }
  }
  if (lane < 32) {
    out[BN * TT * HN + b * HN + col] = h;             // h_t
    out[BN * TT * HN + BN * HN + b * HN + col] = c;   // c_t
  }
}

extern "C" void kernel_launch(void* const* d_in, const int* in_sizes, int n_in,
                              void* d_out, int out_size, void* d_ws, size_t ws_size,
                              hipStream_t stream) {
  (void)in_sizes; (void)n_in; (void)d_ws; (void)ws_size; (void)out_size;
  const float* x  = (const float*)d_in[0];
  const float* Ui = (const float*)d_in[1];
  const float* Vi = (const float*)d_in[2];
  const float* bi = (const float*)d_in[3];
  const float* Uf = (const float*)d_in[4];
  const float* Vf = (const float*)d_in[5];
  const float* bf = (const float*)d_in[6];
  const float* Uc = (const float*)d_in[7];
  const float* Vc = (const float*)d_in[8];
  const float* bc = (const float*)d_in[9];
  const float* Uo = (const float*)d_in[10];
  const float* Vo = (const float*)d_in[11];
  const float* bo = (const float*)d_in[12];
  float* out = (float*)d_out;

  dim3 grid(2560);  // one wave per workgroup -> exactly 10 waves/CU, balanced
  dim3 block(64);
  hipLaunchKernelGGL(lstm_kernel, grid, block, 0, stream,
                     x, Ui, Vi, bi, Uf, Vf, bf, Uc, Vc, bc, Uo, Vo, bo, out);
}